// Round 9
// baseline (403.603 us; speedup 1.0000x reference)
//
#include <hip/hip_runtime.h>
#include <math.h>

#define LEAK 0.01f
#define BNEPS 1e-5f
#define NCH 64    // chunks for hist/scatter phases
#define NGMAX 1024

typedef __attribute__((ext_vector_type(8))) short bf16x8;
typedef __attribute__((ext_vector_type(4))) float f32x4;
typedef __attribute__((ext_vector_type(2))) float f32x2;

// ---------------- bf16 helpers ----------------
__device__ inline unsigned bfpack(float a, float b) {  // two f32 -> packed bf16 (RNE)
  unsigned ua = __float_as_uint(a);
  unsigned ub = __float_as_uint(b);
  unsigned ra = (ua + 0x7fffu + ((ua >> 16) & 1u)) >> 16;
  unsigned rb = (ub + 0x7fffu + ((ub >> 16) & 1u)) & 0xffff0000u;
  return ra | rb;
}
__device__ inline unsigned short bfround(float a) {
  unsigned ua = __float_as_uint(a);
  return (unsigned short)((ua + 0x7fffu + ((ua >> 16) & 1u)) >> 16);
}
__device__ inline float2 bfunpack(unsigned u) {
  float2 r;
  r.x = __uint_as_float(u << 16);
  r.y = __uint_as_float(u & 0xffff0000u);
  return r;
}
// fp8 e4m3 (OCP) helpers via gfx950 HW cvt
__device__ inline unsigned char f32_to_fp8(float v) {
  int p = __builtin_amdgcn_cvt_pk_fp8_f32(v, v, 0, false);
  return (unsigned char)(p & 0xff);
}

// =======================================================================
// CSR build via bucketed counting sort (bucket = dst>>8, NBK<=256)
// =======================================================================
__global__ __launch_bounds__(256) void k_hist(const int* __restrict__ dst,
                                              int* __restrict__ H, int E, int NBK) {
  __shared__ int h[256];
  h[threadIdx.x] = 0;
  __syncthreads();
  int chunk = (E + NCH - 1) / NCH;
  int lo = blockIdx.x * chunk, hi = min(lo + chunk, E);
  for (int e = lo + threadIdx.x; e < hi; e += 256)
    atomicAdd(&h[dst[e] >> 8], 1);
  __syncthreads();
  if (threadIdx.x < NBK) H[threadIdx.x * NCH + blockIdx.x] = h[threadIdx.x];
}

__global__ __launch_bounds__(256) void k_gscan1(const int* __restrict__ in,
                                                int* __restrict__ bsum, int m) {
  int i = blockIdx.x * 256 + threadIdx.x;
  int v = (i < m) ? in[i] : 0;
#pragma unroll
  for (int s = 1; s < 64; s <<= 1) v += __shfl_xor(v, s, 64);
  __shared__ int ws[4];
  if ((threadIdx.x & 63) == 0) ws[threadIdx.x >> 6] = v;
  __syncthreads();
  if (threadIdx.x == 0) bsum[blockIdx.x] = ws[0] + ws[1] + ws[2] + ws[3];
}
__global__ __launch_bounds__(256) void k_gscan2(int* __restrict__ bsum, int NB) {
  __shared__ int lds[256];
  int t = threadIdx.x;
  int v = (t < NB) ? bsum[t] : 0;
  lds[t] = v;
  __syncthreads();
  for (int ofs = 1; ofs < 256; ofs <<= 1) {
    int u = (t >= ofs) ? lds[t - ofs] : 0;
    __syncthreads();
    lds[t] += u;
    __syncthreads();
  }
  if (t < NB) bsum[t] = lds[t] - v;  // exclusive, in-place
}
__global__ __launch_bounds__(256) void k_gscan3(const int* __restrict__ in,
                                                const int* __restrict__ boff,
                                                int* __restrict__ out, int m) {
  __shared__ int lds[256];
  int t = threadIdx.x;
  int i = blockIdx.x * 256 + t;
  int v = (i < m) ? in[i] : 0;
  lds[t] = v;
  __syncthreads();
  for (int ofs = 1; ofs < 256; ofs <<= 1) {
    int u = (t >= ofs) ? lds[t - ofs] : 0;
    __syncthreads();
    lds[t] += u;
    __syncthreads();
  }
  if (i < m) out[i] = boff[blockIdx.x] + lds[t] - v;
}

__global__ __launch_bounds__(256) void k_scatter_bkt(
    const int* __restrict__ src, const int* __restrict__ dst,
    const int* __restrict__ O, int* __restrict__ ebuf, int E, int NBK) {
  __shared__ int cur[256];
  if (threadIdx.x < NBK) cur[threadIdx.x] = O[threadIdx.x * NCH + blockIdx.x];
  __syncthreads();
  int chunk = (E + NCH - 1) / NCH;
  int lo = blockIdx.x * chunk, hi = min(lo + chunk, E);
  for (int e = lo + threadIdx.x; e < hi; e += 256) {
    int d = dst[e];
    int pos = atomicAdd(&cur[d >> 8], 1);
    ebuf[pos] = src[e] | ((d & 255) << 24);   // requires n < 2^24
  }
}

__global__ __launch_bounds__(256) void k_fill2(
    const int* __restrict__ ebuf, const int* __restrict__ O,
    int* __restrict__ eidx, int* __restrict__ rowptr,
    float* __restrict__ dinv, float* __restrict__ invcnt,
    int E, int n, int NBK) {
  __shared__ int hist[256];
  __shared__ int sc[256];
  __shared__ int cur[256];
  const int b = blockIdx.x;
  const int t = threadIdx.x;
  const int lo = O[b * NCH];
  const int hi = (b + 1 < NBK) ? O[(b + 1) * NCH] : E;
  hist[t] = 0;
  __syncthreads();
  for (int e = lo + t; e < hi; e += 256)
    atomicAdd(&hist[(ebuf[e] >> 24) & 255], 1);
  __syncthreads();
  int v = hist[t];
  sc[t] = v;
  __syncthreads();
  for (int ofs = 1; ofs < 256; ofs <<= 1) {
    int u = (t >= ofs) ? sc[t - ofs] : 0;
    __syncthreads();
    sc[t] += u;
    __syncthreads();
  }
  int excl = sc[t] - v;
  cur[t] = lo + excl;
  int node = b * 256 + t;
  if (node < n) {
    rowptr[node] = lo + excl;
    float d = (float)v;
    dinv[node]   = rsqrtf(d + 1.0f);
    invcnt[node] = 1.0f / fmaxf(d, 1.0f);
  }
  if (node == n || (b == NBK - 1 && t == 255)) rowptr[n] = E;
  __syncthreads();
  for (int e = lo + t; e < hi; e += 256) {
    int p = ebuf[e];
    int pos = atomicAdd(&cur[(p >> 24) & 255], 1);
    eidx[pos] = p & 0xFFFFFF;
  }
}

// =======================================================================
// CSR gather aggregation over bf16 rows (one wave per node)
// =======================================================================
template<int F, bool GCN, bool OUTBF, bool ADD>
__global__ __launch_bounds__(256) void k_gather(
    const unsigned short* __restrict__ Hs, const float* __restrict__ scale,
    const int* __restrict__ rowptr, const int* __restrict__ eidx,
    const float* __restrict__ bias, const float* __restrict__ addf,
    float* __restrict__ outf, unsigned short* __restrict__ outb, int n) {
  constexpr int COLS = F / 8;       // lanes per edge (8 bf16 = 16 B each)
  constexpr int EPI  = 64 / COLS;   // edges per iteration
  const int v = blockIdx.x * 4 + (threadIdx.x >> 6);
  if (v >= n) return;
  const int lane = threadIdx.x & 63;
  const int col  = lane % COLS;
  const int eo   = lane / COLS;

  const int lo = rowptr[v], hi = rowptr[v + 1];
  float a[8] = {0.f,0.f,0.f,0.f,0.f,0.f,0.f,0.f};
  int myE = (lo + lane < hi) ? eidx[lo + lane] : 0;
  for (int base = lo; base < hi; base += 64) {
    int cnt = min(hi - base, 64);
    int nxt = (base + 64 + lane < hi) ? eidx[base + 64 + lane] : 0;
#pragma unroll 4
    for (int t = eo; t < cnt; t += EPI) {
      int s = __shfl(myE, t, 64);
      uint4 hv = *(const uint4*)&Hs[(long long)s * F + col * 8];
      float2 p0 = bfunpack(hv.x), p1 = bfunpack(hv.y);
      float2 p2 = bfunpack(hv.z), p3 = bfunpack(hv.w);
      a[0]+=p0.x; a[1]+=p0.y; a[2]+=p1.x; a[3]+=p1.y;
      a[4]+=p2.x; a[5]+=p2.y; a[6]+=p3.x; a[7]+=p3.y;
    }
    myE = nxt;
  }
#pragma unroll
  for (int m = COLS; m < 64; m <<= 1) {
#pragma unroll
    for (int j = 0; j < 8; j++) a[j] += __shfl_xor(a[j], m, 64);
  }
  if (eo == 0) {
    float sv = scale[v];
    float o[8];
    if constexpr (GCN) {
      uint4 hv = *(const uint4*)&Hs[(long long)v * F + col * 8];
      float2 p0 = bfunpack(hv.x), p1 = bfunpack(hv.y);
      float2 p2 = bfunpack(hv.z), p3 = bfunpack(hv.w);
      float h[8] = {p0.x,p0.y,p1.x,p1.y,p2.x,p2.y,p3.x,p3.y};
#pragma unroll
      for (int j = 0; j < 8; j++) o[j] = bias[col * 8 + j] + sv * (a[j] + h[j]);
    } else if constexpr (ADD) {
      const float4 t0 = *(const float4*)&addf[(long long)v * F + col * 8];
      const float4 t1 = *(const float4*)&addf[(long long)v * F + col * 8 + 4];
      o[0]=fmaf(sv,a[0],t0.x); o[1]=fmaf(sv,a[1],t0.y);
      o[2]=fmaf(sv,a[2],t0.z); o[3]=fmaf(sv,a[3],t0.w);
      o[4]=fmaf(sv,a[4],t1.x); o[5]=fmaf(sv,a[5],t1.y);
      o[6]=fmaf(sv,a[6],t1.z); o[7]=fmaf(sv,a[7],t1.w);
    } else {
#pragma unroll
      for (int j = 0; j < 8; j++) o[j] = sv * a[j];
    }
    if constexpr (OUTBF) {
      uint4 u;
      u.x = bfpack(o[0], o[1]); u.y = bfpack(o[2], o[3]);
      u.z = bfpack(o[4], o[5]); u.w = bfpack(o[6], o[7]);
      *(uint4*)&outb[(long long)v * F + col * 8] = u;
    } else {
      float4 o0 = {o[0],o[1],o[2],o[3]}, o1 = {o[4],o[5],o[6],o[7]};
      *(float4*)&outf[(long long)v * F + col * 8]     = o0;
      *(float4*)&outf[(long long)v * F + col * 8 + 4] = o1;
    }
  }
}

// ==== GCN gather with fp8 e4m3 neighbor rows (F=128); self term from bf16 ===
__global__ __launch_bounds__(256) void k_gather_gcn_fp8(
    const unsigned char* __restrict__ Hf8, const unsigned short* __restrict__ Hbf,
    const float* __restrict__ scale,
    const int* __restrict__ rowptr, const int* __restrict__ eidx,
    const float* __restrict__ bias, unsigned short* __restrict__ outb, int n) {
  constexpr int F = 128, COLS = 16, EPI = 4;  // 8 fp8 = 8 B per lane
  const int v = blockIdx.x * 4 + (threadIdx.x >> 6);
  if (v >= n) return;
  const int lane = threadIdx.x & 63;
  const int col  = lane % COLS;
  const int eo   = lane / COLS;

  const int lo = rowptr[v], hi = rowptr[v + 1];
  float a[8] = {0.f,0.f,0.f,0.f,0.f,0.f,0.f,0.f};
  int myE = (lo + lane < hi) ? eidx[lo + lane] : 0;
  for (int base = lo; base < hi; base += 64) {
    int cnt = min(hi - base, 64);
    int nxt = (base + 64 + lane < hi) ? eidx[base + 64 + lane] : 0;
#pragma unroll 4
    for (int t = eo; t < cnt; t += EPI) {
      int s = __shfl(myE, t, 64);
      uint2 q = *(const uint2*)&Hf8[(long long)s * F + col * 8];
      f32x2 p0 = __builtin_amdgcn_cvt_pk_f32_fp8(q.x, false);
      f32x2 p1 = __builtin_amdgcn_cvt_pk_f32_fp8(q.x, true);
      f32x2 p2 = __builtin_amdgcn_cvt_pk_f32_fp8(q.y, false);
      f32x2 p3 = __builtin_amdgcn_cvt_pk_f32_fp8(q.y, true);
      a[0]+=p0[0]; a[1]+=p0[1]; a[2]+=p1[0]; a[3]+=p1[1];
      a[4]+=p2[0]; a[5]+=p2[1]; a[6]+=p3[0]; a[7]+=p3[1];
    }
    myE = nxt;
  }
#pragma unroll
  for (int m = COLS; m < 64; m <<= 1) {
#pragma unroll
    for (int j = 0; j < 8; j++) a[j] += __shfl_xor(a[j], m, 64);
  }
  if (eo == 0) {
    float sv = scale[v];
    uint4 hv = *(const uint4*)&Hbf[(long long)v * F + col * 8];
    float2 p0 = bfunpack(hv.x), p1 = bfunpack(hv.y);
    float2 p2 = bfunpack(hv.z), p3 = bfunpack(hv.w);
    float h[8] = {p0.x,p0.y,p1.x,p1.y,p2.x,p2.y,p3.x,p3.y};
    float o[8];
#pragma unroll
    for (int j = 0; j < 8; j++) o[j] = bias[col * 8 + j] + sv * (a[j] + h[j]);
    uint4 u;
    u.x = bfpack(o[0], o[1]); u.y = bfpack(o[2], o[3]);
    u.z = bfpack(o[4], o[5]); u.w = bfpack(o[6], o[7]);
    *(uint4*)&outb[(long long)v * F + col * 8] = u;
  }
}

// =======================================================================
// MFMA GEMM: Yb = bf16(prescale * (act(X) @ W)); optional fp8 copy (F8OUT).
// =======================================================================
template<int K, int F, bool XBF, bool BNIN, bool F8OUT>
__global__ __launch_bounds__(256) void k_gemm_mfma(
    const void* __restrict__ Xv, const float* __restrict__ W,
    const float* __restrict__ bnstats, const float* __restrict__ prescale,
    unsigned short* __restrict__ Yb, unsigned char* __restrict__ Yf8, int n) {
  constexpr int SP  = K + 8;      // padded LDS row stride (shorts)
  constexpr int NCT = F / 16;     // col-tiles per wave
  __shared__ unsigned short sX[64 * SP];
  __shared__ unsigned short sWT[F * SP];
  __shared__ float sbn[BNIN ? 2 * K : 1];

  const int row0 = blockIdx.x * 64;
  if constexpr (BNIN) {
    for (int i = threadIdx.x; i < 2 * K; i += 256) sbn[i] = bnstats[i];
    __syncthreads();
  }
  for (int i = threadIdx.x; i < (K / 2) * F; i += 256) {
    int nn = i % F;
    int kk = (i / F) * 2;
    float w0 = W[(long long)kk * F + nn];
    float w1 = W[(long long)(kk + 1) * F + nn];
    *(unsigned*)&sWT[nn * SP + kk] = bfpack(w0, w1);
  }
  for (int i = threadIdx.x; i < 64 * (K / 8); i += 256) {
    int r = i / (K / 8), k8 = (i % (K / 8)) * 8;
    int gr = row0 + r;
    uint4 u = {0, 0, 0, 0};
    if (gr < n) {
      if constexpr (XBF) {
        const unsigned short* X = (const unsigned short*)Xv;
        uint4 raw = *(const uint4*)&X[(long long)gr * K + k8];
        if constexpr (BNIN) {
          float2 p0 = bfunpack(raw.x), p1 = bfunpack(raw.y);
          float2 p2 = bfunpack(raw.z), p3 = bfunpack(raw.w);
          float y[8] = {p0.x,p0.y,p1.x,p1.y,p2.x,p2.y,p3.x,p3.y};
#pragma unroll
          for (int j = 0; j < 8; j++) {
            float t = fmaf(y[j], sbn[k8 + j], sbn[K + k8 + j]);
            y[j] = (t >= 0.f) ? t : LEAK * t;
          }
          u.x = bfpack(y[0], y[1]); u.y = bfpack(y[2], y[3]);
          u.z = bfpack(y[4], y[5]); u.w = bfpack(y[6], y[7]);
        } else {
          u = raw;
        }
      } else {
        const float* X = (const float*)Xv;
        float4 xa = *(const float4*)&X[(long long)gr * K + k8];
        float4 xb = *(const float4*)&X[(long long)gr * K + k8 + 4];
        u.x = bfpack(xa.x, xa.y); u.y = bfpack(xa.z, xa.w);
        u.z = bfpack(xb.x, xb.y); u.w = bfpack(xb.z, xb.w);
      }
    }
    *(uint4*)&sX[r * SP + k8] = u;
  }
  __syncthreads();

  const int wv   = threadIdx.x >> 6;
  const int lane = threadIdx.x & 63;
  const int l16  = lane & 15;
  const int quad = lane >> 4;
  f32x4 acc[NCT];
#pragma unroll
  for (int c = 0; c < NCT; c++) acc[c] = (f32x4){0.f, 0.f, 0.f, 0.f};

#pragma unroll
  for (int k0 = 0; k0 < K; k0 += 32) {
    bf16x8 af = *(const bf16x8*)&sX[(wv * 16 + l16) * SP + k0 + quad * 8];
#pragma unroll
    for (int c = 0; c < NCT; c++) {
      bf16x8 bfr = *(const bf16x8*)&sWT[(c * 16 + l16) * SP + k0 + quad * 8];
      acc[c] = __builtin_amdgcn_mfma_f32_16x16x32_bf16(af, bfr, acc[c], 0, 0, 0);
    }
  }

  const int rbase = row0 + wv * 16 + quad * 4;
  float ps[4];
#pragma unroll
  for (int rg = 0; rg < 4; rg++) {
    int gr = rbase + rg;
    ps[rg] = (prescale && gr < n) ? prescale[gr] : 1.0f;
  }
#pragma unroll
  for (int c = 0; c < NCT; c++) {
    int col = c * 16 + l16;
#pragma unroll
    for (int rg = 0; rg < 4; rg++) {
      int gr = rbase + rg;
      if (gr < n) {
        float val = acc[c][rg] * ps[rg];
        Yb[(long long)gr * F + col] = bfround(val);
        if constexpr (F8OUT) Yf8[(long long)gr * F + col] = f32_to_fp8(val);
      }
    }
  }
}

// ==== SAGE dual MFMA GEMM (BN+lrelu fused): t1=X'@Wl bf16, t2=X'@Wr+bl f32 ==
__global__ __launch_bounds__(256) void k_gemm_sage_mfma(
    const unsigned short* __restrict__ X, const float* __restrict__ Wl,
    const float* __restrict__ Wr, const float* __restrict__ bl,
    const float* __restrict__ bnstats,
    unsigned short* __restrict__ t1, float* __restrict__ t2, int n) {
  constexpr int K = 128, F = 64, SP = K + 8, NCT = F / 16;  // 4
  __shared__ unsigned short sX[64 * SP];
  __shared__ unsigned short sWlT[F * SP];
  __shared__ unsigned short sWrT[F * SP];
  __shared__ float sbn[2 * K];

  for (int i = threadIdx.x; i < 2 * K; i += 256) sbn[i] = bnstats[i];
  __syncthreads();
  const int row0 = blockIdx.x * 64;
  for (int i = threadIdx.x; i < (K / 2) * F; i += 256) {
    int nn = i % F;
    int kk = (i / F) * 2;
    *(unsigned*)&sWlT[nn * SP + kk] =
        bfpack(Wl[(long long)kk * F + nn], Wl[(long long)(kk + 1) * F + nn]);
    *(unsigned*)&sWrT[nn * SP + kk] =
        bfpack(Wr[(long long)kk * F + nn], Wr[(long long)(kk + 1) * F + nn]);
  }
  for (int i = threadIdx.x; i < 64 * (K / 8); i += 256) {
    int r = i / (K / 8), k8 = (i % (K / 8)) * 8;
    int gr = row0 + r;
    uint4 u = {0, 0, 0, 0};
    if (gr < n) {
      uint4 raw = *(const uint4*)&X[(long long)gr * K + k8];
      float2 p0 = bfunpack(raw.x), p1 = bfunpack(raw.y);
      float2 p2 = bfunpack(raw.z), p3 = bfunpack(raw.w);
      float y[8] = {p0.x,p0.y,p1.x,p1.y,p2.x,p2.y,p3.x,p3.y};
#pragma unroll
      for (int j = 0; j < 8; j++) {
        float t = fmaf(y[j], sbn[k8 + j], sbn[K + k8 + j]);
        y[j] = (t >= 0.f) ? t : LEAK * t;
      }
      u.x = bfpack(y[0], y[1]); u.y = bfpack(y[2], y[3]);
      u.z = bfpack(y[4], y[5]); u.w = bfpack(y[6], y[7]);
    }
    *(uint4*)&sX[r * SP + k8] = u;
  }
  __syncthreads();

  const int wv   = threadIdx.x >> 6;
  const int lane = threadIdx.x & 63;
  const int l16  = lane & 15;
  const int quad = lane >> 4;
  f32x4 a1[NCT], a2[NCT];
#pragma unroll
  for (int c = 0; c < NCT; c++) {
    a1[c] = (f32x4){0.f, 0.f, 0.f, 0.f};
    a2[c] = (f32x4){0.f, 0.f, 0.f, 0.f};
  }
#pragma unroll
  for (int k0 = 0; k0 < K; k0 += 32) {
    bf16x8 af = *(const bf16x8*)&sX[(wv * 16 + l16) * SP + k0 + quad * 8];
#pragma unroll
    for (int c = 0; c < NCT; c++) {
      bf16x8 bl8 = *(const bf16x8*)&sWlT[(c * 16 + l16) * SP + k0 + quad * 8];
      bf16x8 br8 = *(const bf16x8*)&sWrT[(c * 16 + l16) * SP + k0 + quad * 8];
      a1[c] = __builtin_amdgcn_mfma_f32_16x16x32_bf16(af, bl8, a1[c], 0, 0, 0);
      a2[c] = __builtin_amdgcn_mfma_f32_16x16x32_bf16(af, br8, a2[c], 0, 0, 0);
    }
  }
  const int rbase = row0 + wv * 16 + quad * 4;
#pragma unroll
  for (int c = 0; c < NCT; c++) {
    int col = c * 16 + l16;
    float blv = bl[col];
#pragma unroll
    for (int rg = 0; rg < 4; rg++) {
      int gr = rbase + rg;
      if (gr < n) {
        t1[(long long)gr * F + col] = bfround(a1[c][rg]);
        t2[(long long)gr * F + col] = a2[c][rg] + blv;
      }
    }
  }
}

// ---------------- BatchNorm stats (from bf16 pre-BN buffer) ----------------
template<int F>
__global__ __launch_bounds__(256) void k_bn_stats(const unsigned short* __restrict__ Y,
                                                  float* __restrict__ partials, int n) {
  constexpr int FP  = F / 2;
  constexpr int RPB = 256 / FP;
  const int f2 = threadIdx.x % FP;
  const int r0 = threadIdx.x / FP;
  const unsigned* Yu = (const unsigned*)Y;
  float s1a = 0.f, s2a = 0.f, s1b = 0.f, s2b = 0.f;
  for (long long r = (long long)blockIdx.x * RPB + r0; r < n; r += 256LL * RPB) {
    float2 p = bfunpack(Yu[r * FP + f2]);
    s1a += p.x; s2a += p.x * p.x;
    s1b += p.y; s2b += p.y * p.y;
  }
  __shared__ float l1a[256], l2a[256], l1b[256], l2b[256];
  l1a[threadIdx.x] = s1a; l2a[threadIdx.x] = s2a;
  l1b[threadIdx.x] = s1b; l2b[threadIdx.x] = s2b;
  __syncthreads();
  if (r0 == 0) {
#pragma unroll
    for (int i = 1; i < RPB; i++) {
      s1a += l1a[i * FP + f2]; s2a += l2a[i * FP + f2];
      s1b += l1b[i * FP + f2]; s2b += l2b[i * FP + f2];
    }
    float* p = &partials[blockIdx.x * 2 * F];
    p[2 * f2]         = s1a;
    p[2 * f2 + 1]     = s1b;
    p[F + 2 * f2]     = s2a;
    p[F + 2 * f2 + 1] = s2b;
  }
}

__global__ void k_bn_finalize(const float* __restrict__ partials, float* __restrict__ stats,
                              const float* __restrict__ g, const float* __restrict__ be,
                              int F, float invN) {
  int f = threadIdx.x;
  if (f >= F) return;
  float s1 = 0.f, s2 = 0.f;
  for (int b = 0; b < 256; b++) {
    s1 += partials[b * 2 * F + f];
    s2 += partials[b * 2 * F + F + f];
  }
  float m   = s1 * invN;
  float var = s2 * invN - m * m;
  float sc  = g[f] * rsqrtf(var + BNEPS);
  stats[f]     = sc;
  stats[F + f] = be[f] - m * sc;
}

// ---------------- pool (batch sorted; binary search per graph) + link ------
__global__ __launch_bounds__(256) void k_pool2(const float* __restrict__ a4,
                                               const int* __restrict__ batch,
                                               float* __restrict__ gpool, int n) {
  int g = blockIdx.x * 4 + (threadIdx.x >> 6);
  if (g >= NGMAX) return;
  int lane = threadIdx.x & 63;
  int s = 0, e = n;
  while (s < e) { int m = (s + e) >> 1; if (batch[m] < g) s = m + 1; else e = m; }
  int s2 = s, e2 = n;
  while (s2 < e2) { int m = (s2 + e2) >> 1; if (batch[m] < g + 1) s2 = m + 1; else e2 = m; }
  int f = lane & 31, ro = lane >> 5;
  float acc = 0.f;
  for (int r = s + ro; r < s2; r += 2) acc += a4[(long long)r * 32 + f];
  acc += __shfl_xor(acc, 32, 64);
  if (lane < 32) gpool[(long long)g * 32 + f] = acc;
}

__global__ void k_link(const float* __restrict__ g, const int* __restrict__ li0,
                       const int* __restrict__ li1, float* __restrict__ out, int L) {
  int i = blockIdx.x * blockDim.x + threadIdx.x;
  if (i >= L) return;
  const float* a = g + (long long)li0[i] * 32;
  const float* b = g + (long long)li1[i] * 32;
  float s = 0.f;
#pragma unroll
  for (int f = 0; f < 32; f++) s = fmaf(a[f], b[f], s);
  out[i] = 1.0f / (1.0f + expf(-s));
}

// ---------------- launch ----------------
extern "C" void kernel_launch(void* const* d_in, const int* in_sizes, int n_in,
                              void* d_out, int out_size, void* d_ws, size_t ws_size,
                              hipStream_t stream) {
  const float* x   = (const float*)d_in[0];
  const int* ei    = (const int*)d_in[1];
  const int* batch = (const int*)d_in[2];
  const int* li    = (const int*)d_in[3];
  const float* W1  = (const float*)d_in[5];
  const float* b1  = (const float*)d_in[6];
  const float* g1  = (const float*)d_in[7];
  const float* be1 = (const float*)d_in[8];
  const float* Wl2 = (const float*)d_in[9];
  const float* bl2 = (const float*)d_in[10];
  const float* Wr2 = (const float*)d_in[11];
  const float* g2  = (const float*)d_in[12];
  const float* be2 = (const float*)d_in[13];
  const float* W3  = (const float*)d_in[14];
  const float* b3  = (const float*)d_in[15];
  const float* g3  = (const float*)d_in[16];
  const float* be3 = (const float*)d_in[17];
  const float* W4  = (const float*)d_in[18];
  const float* b4  = (const float*)d_in[19];

  const int n = in_sizes[0] / 128;   // 50000
  const int E = in_sizes[1] / 2;     // 800000
  const int L = in_sizes[3] / 2;     // 1000
  const int* src = ei;
  const int* dst = ei + E;
  const int* li0 = li;
  const int* li1 = li + L;
  const int NBK = (n + 255) / 256;   // dst buckets (<=256 for n<=65536)

  char* base = (char*)d_ws;
  size_t off = 0;
  auto alloc = [&](size_t bytes) -> void* {
    void* p = (void*)(base + off);
    off = (off + bytes + 255) & ~(size_t)255;
    return p;
  };
  int*   H      = (int*)alloc((size_t)NBK * NCH * 4);
  int*   O      = (int*)alloc((size_t)NBK * NCH * 4);
  int*   hsum   = (int*)alloc(1024 * 4);
  int*   ebuf   = (int*)alloc((size_t)E * 4);
  int*   eidx   = (int*)alloc((size_t)E * 4);
  int*   rowptr = (int*)alloc((size_t)(n + 1) * 4);
  float* dinv   = (float*)alloc((size_t)n * 4);
  float* invcnt = (float*)alloc((size_t)n * 4);
  float* stats1 = (float*)alloc(256 * 4);
  float* stats2 = (float*)alloc(128 * 4);
  float* stats3 = (float*)alloc(64 * 4);
  float* partials = (float*)alloc((size_t)256 * 256 * 4);
  float* gpool  = (float*)alloc((size_t)NGMAX * 32 * 4);
  unsigned short* h1b  = (unsigned short*)alloc((size_t)n * 128 * 2); // dinv*(x@W1) bf16
  unsigned char*  h1f8 = (unsigned char*)alloc((size_t)n * 128);     // same, fp8 e4m3
  unsigned short* a1b  = (unsigned short*)alloc((size_t)n * 128 * 2); // pre-BN a1
  unsigned short* t1b  = (unsigned short*)alloc((size_t)n * 64 * 2);  // h1'@Wl2
  float*          t2f  = (float*)alloc((size_t)n * 64 * 4);           // h1'@Wr2+bl2
  unsigned short* h2b  = (unsigned short*)alloc((size_t)n * 64 * 2);  // pre-BN h2
  unsigned short* h3gb = (unsigned short*)alloc((size_t)n * 32 * 2);  // dinv*(h2'@W3)
  unsigned short* a3b  = (unsigned short*)alloc((size_t)n * 32 * 2);  // pre-BN a3
  unsigned short* h4b  = (unsigned short*)alloc((size_t)n * 32 * 2);  // dinv*(h3'@W4)
  float*          a4f  = (float*)alloc((size_t)n * 32 * 4);           // a4 (fp32)
  (void)ws_size; (void)n_in; (void)out_size;

  const int BT = 256;
  auto cdiv = [](long long a, long long b) { return (int)((a + b - 1) / b); };
  const int GB  = cdiv(n, 4);                 // gather grid
  const int GM  = cdiv(n, 64);                // mfma gemm grid
  const int MH  = NBK * NCH;                  // histogram elements
  const int NBH = cdiv(MH, 256);              // scan blocks

  // ---- CSR build: bucketed counting sort ----
  k_hist<<<NCH, 256, 0, stream>>>(dst, H, E, NBK);
  k_gscan1<<<NBH, 256, 0, stream>>>(H, hsum, MH);
  k_gscan2<<<1, 256, 0, stream>>>(hsum, NBH);
  k_gscan3<<<NBH, 256, 0, stream>>>(H, hsum, O, MH);
  k_scatter_bkt<<<NCH, 256, 0, stream>>>(src, dst, O, ebuf, E, NBK);
  k_fill2<<<NBK, 256, 0, stream>>>(ebuf, O, eidx, rowptr, dinv, invcnt, E, n, NBK);

  // ---- L1: GCN 128->128 (MFMA; emits bf16 + fp8 copies) ----
  k_gemm_mfma<128,128,false,false,true><<<GM, 256, 0, stream>>>(
      x, W1, nullptr, dinv, h1b, h1f8, n);
  k_gather_gcn_fp8<<<GB, 256, 0, stream>>>(
      h1f8, h1b, dinv, rowptr, eidx, b1, a1b, n);
  k_bn_stats<128><<<256, 256, 0, stream>>>(a1b, partials, n);
  k_bn_finalize<<<1, 128, 0, stream>>>(partials, stats1, g1, be1, 128, 1.0f / n);

  // ---- L2: SAGE 128->64 (MFMA dual, BN1+lrelu fused) ----
  k_gemm_sage_mfma<<<GM, 256, 0, stream>>>(a1b, Wl2, Wr2, bl2, stats1, t1b, t2f, n);
  k_gather<64,false,true,true><<<GB, 256, 0, stream>>>(
      t1b, invcnt, rowptr, eidx, nullptr, t2f, nullptr, h2b, n);
  k_bn_stats<64><<<256, 256, 0, stream>>>(h2b, partials, n);
  k_bn_finalize<<<1, 64, 0, stream>>>(partials, stats2, g2, be2, 64, 1.0f / n);

  // ---- L3: GCN 64->32 (MFMA, BN2+lrelu fused) ----
  k_gemm_mfma<64,32,true,true,false><<<GM, 256, 0, stream>>>(
      h2b, W3, stats2, dinv, h3gb, nullptr, n);
  k_gather<32,true,true,false><<<GB, 256, 0, stream>>>(
      h3gb, dinv, rowptr, eidx, b3, nullptr, nullptr, a3b, n);
  k_bn_stats<32><<<256, 256, 0, stream>>>(a3b, partials, n);
  k_bn_finalize<<<1, 32, 0, stream>>>(partials, stats3, g3, be3, 32, 1.0f / n);

  // ---- L4: GCN 32->32 (MFMA, BN3+lrelu fused), fp32 out via gather ----
  k_gemm_mfma<32,32,true,true,false><<<GM, 256, 0, stream>>>(
      a3b, W4, stats3, dinv, h4b, nullptr, n);
  k_gather<32,true,false,false><<<GB, 256, 0, stream>>>(
      h4b, dinv, rowptr, eidx, b4, nullptr, a4f, nullptr, n);

  // ---- pool (no atomics; batch sorted) + link ----
  k_pool2<<<NGMAX / 4, 256, 0, stream>>>(a4f, batch, gpool, n);
  k_link<<<cdiv(L, BT), BT, 0, stream>>>(gpool, li0, li1, (float*)d_out, L);
}

// Round 10
// 379.277 us; speedup vs baseline: 1.0641x; 1.0641x over previous
//
#include <hip/hip_runtime.h>
#include <math.h>

#define LEAK 0.01f
#define BNEPS 1e-5f
#define NCH 256   // chunks for hist/scatter phases (256 blocks: keep grid wide)
#define NGMAX 1024

typedef __attribute__((ext_vector_type(8))) short bf16x8;
typedef __attribute__((ext_vector_type(4))) float f32x4;
typedef __attribute__((ext_vector_type(2))) float f32x2;

// ---------------- bf16 helpers ----------------
__device__ inline unsigned bfpack(float a, float b) {  // two f32 -> packed bf16 (RNE)
  unsigned ua = __float_as_uint(a);
  unsigned ub = __float_as_uint(b);
  unsigned ra = (ua + 0x7fffu + ((ua >> 16) & 1u)) >> 16;
  unsigned rb = (ub + 0x7fffu + ((ub >> 16) & 1u)) & 0xffff0000u;
  return ra | rb;
}
__device__ inline unsigned short bfround(float a) {
  unsigned ua = __float_as_uint(a);
  return (unsigned short)((ua + 0x7fffu + ((ua >> 16) & 1u)) >> 16);
}
__device__ inline float2 bfunpack(unsigned u) {
  float2 r;
  r.x = __uint_as_float(u << 16);
  r.y = __uint_as_float(u & 0xffff0000u);
  return r;
}
// fp8 e4m3 (OCP) helpers via gfx950 HW cvt
__device__ inline unsigned char f32_to_fp8(float v) {
  int p = __builtin_amdgcn_cvt_pk_fp8_f32(v, v, 0, false);
  return (unsigned char)(p & 0xff);
}

// =======================================================================
// CSR build via bucketed counting sort (bucket = dst>>8, NBK<=256)
// =======================================================================
__global__ __launch_bounds__(256) void k_hist(const int* __restrict__ dst,
                                              int* __restrict__ H, int E, int NBK) {
  __shared__ int h[256];
  h[threadIdx.x] = 0;
  __syncthreads();
  int chunk = (E + NCH - 1) / NCH;
  int lo = blockIdx.x * chunk, hi = min(lo + chunk, E);
  for (int e = lo + threadIdx.x; e < hi; e += 256)
    atomicAdd(&h[dst[e] >> 8], 1);
  __syncthreads();
  if (threadIdx.x < NBK) H[threadIdx.x * NCH + blockIdx.x] = h[threadIdx.x];
}

__global__ __launch_bounds__(256) void k_gscan1(const int* __restrict__ in,
                                                int* __restrict__ bsum, int m) {
  int i = blockIdx.x * 256 + threadIdx.x;
  int v = (i < m) ? in[i] : 0;
#pragma unroll
  for (int s = 1; s < 64; s <<= 1) v += __shfl_xor(v, s, 64);
  __shared__ int ws[4];
  if ((threadIdx.x & 63) == 0) ws[threadIdx.x >> 6] = v;
  __syncthreads();
  if (threadIdx.x == 0) bsum[blockIdx.x] = ws[0] + ws[1] + ws[2] + ws[3];
}
__global__ __launch_bounds__(256) void k_gscan2(int* __restrict__ bsum, int NB) {
  __shared__ int lds[256];
  int t = threadIdx.x;
  int v = (t < NB) ? bsum[t] : 0;
  lds[t] = v;
  __syncthreads();
  for (int ofs = 1; ofs < 256; ofs <<= 1) {
    int u = (t >= ofs) ? lds[t - ofs] : 0;
    __syncthreads();
    lds[t] += u;
    __syncthreads();
  }
  if (t < NB) bsum[t] = lds[t] - v;  // exclusive, in-place
}
__global__ __launch_bounds__(256) void k_gscan3(const int* __restrict__ in,
                                                const int* __restrict__ boff,
                                                int* __restrict__ out, int m) {
  __shared__ int lds[256];
  int t = threadIdx.x;
  int i = blockIdx.x * 256 + t;
  int v = (i < m) ? in[i] : 0;
  lds[t] = v;
  __syncthreads();
  for (int ofs = 1; ofs < 256; ofs <<= 1) {
    int u = (t >= ofs) ? lds[t - ofs] : 0;
    __syncthreads();
    lds[t] += u;
    __syncthreads();
  }
  if (i < m) out[i] = boff[blockIdx.x] + lds[t] - v;
}

__global__ __launch_bounds__(256) void k_scatter_bkt(
    const int* __restrict__ src, const int* __restrict__ dst,
    const int* __restrict__ O, int* __restrict__ ebuf, int E, int NBK) {
  __shared__ int cur[256];
  if (threadIdx.x < NBK) cur[threadIdx.x] = O[threadIdx.x * NCH + blockIdx.x];
  __syncthreads();
  int chunk = (E + NCH - 1) / NCH;
  int lo = blockIdx.x * chunk, hi = min(lo + chunk, E);
  for (int e = lo + threadIdx.x; e < hi; e += 256) {
    int d = dst[e];
    int pos = atomicAdd(&cur[d >> 8], 1);
    ebuf[pos] = src[e] | ((d & 255) << 24);   // requires n < 2^24
  }
}

__global__ __launch_bounds__(256) void k_fill2(
    const int* __restrict__ ebuf, const int* __restrict__ O,
    int* __restrict__ eidx, int* __restrict__ rowptr,
    float* __restrict__ dinv, float* __restrict__ invcnt,
    int E, int n, int NBK) {
  __shared__ int hist[256];
  __shared__ int sc[256];
  __shared__ int cur[256];
  const int b = blockIdx.x;
  const int t = threadIdx.x;
  const int lo = O[b * NCH];
  const int hi = (b + 1 < NBK) ? O[(b + 1) * NCH] : E;
  hist[t] = 0;
  __syncthreads();
  for (int e = lo + t; e < hi; e += 256)
    atomicAdd(&hist[(ebuf[e] >> 24) & 255], 1);
  __syncthreads();
  int v = hist[t];
  sc[t] = v;
  __syncthreads();
  for (int ofs = 1; ofs < 256; ofs <<= 1) {
    int u = (t >= ofs) ? sc[t - ofs] : 0;
    __syncthreads();
    sc[t] += u;
    __syncthreads();
  }
  int excl = sc[t] - v;
  cur[t] = lo + excl;
  int node = b * 256 + t;
  if (node < n) {
    rowptr[node] = lo + excl;
    float d = (float)v;
    dinv[node]   = rsqrtf(d + 1.0f);
    invcnt[node] = 1.0f / fmaxf(d, 1.0f);
  }
  if (node == n || (b == NBK - 1 && t == 255)) rowptr[n] = E;
  __syncthreads();
  for (int e = lo + t; e < hi; e += 256) {
    int p = ebuf[e];
    int pos = atomicAdd(&cur[(p >> 24) & 255], 1);
    eidx[pos] = p & 0xFFFFFF;
  }
}

// =======================================================================
// CSR gather aggregation over bf16 rows (one wave per node)
// =======================================================================
template<int F, bool GCN, bool OUTBF, bool ADD>
__global__ __launch_bounds__(256) void k_gather(
    const unsigned short* __restrict__ Hs, const float* __restrict__ scale,
    const int* __restrict__ rowptr, const int* __restrict__ eidx,
    const float* __restrict__ bias, const float* __restrict__ addf,
    float* __restrict__ outf, unsigned short* __restrict__ outb, int n) {
  constexpr int COLS = F / 8;       // lanes per edge (8 bf16 = 16 B each)
  constexpr int EPI  = 64 / COLS;   // edges per iteration
  const int v = blockIdx.x * 4 + (threadIdx.x >> 6);
  if (v >= n) return;
  const int lane = threadIdx.x & 63;
  const int col  = lane % COLS;
  const int eo   = lane / COLS;

  const int lo = rowptr[v], hi = rowptr[v + 1];
  float a[8] = {0.f,0.f,0.f,0.f,0.f,0.f,0.f,0.f};
  int myE = (lo + lane < hi) ? eidx[lo + lane] : 0;
  for (int base = lo; base < hi; base += 64) {
    int cnt = min(hi - base, 64);
    int nxt = (base + 64 + lane < hi) ? eidx[base + 64 + lane] : 0;
#pragma unroll 4
    for (int t = eo; t < cnt; t += EPI) {
      int s = __shfl(myE, t, 64);
      uint4 hv = *(const uint4*)&Hs[(long long)s * F + col * 8];
      float2 p0 = bfunpack(hv.x), p1 = bfunpack(hv.y);
      float2 p2 = bfunpack(hv.z), p3 = bfunpack(hv.w);
      a[0]+=p0.x; a[1]+=p0.y; a[2]+=p1.x; a[3]+=p1.y;
      a[4]+=p2.x; a[5]+=p2.y; a[6]+=p3.x; a[7]+=p3.y;
    }
    myE = nxt;
  }
#pragma unroll
  for (int m = COLS; m < 64; m <<= 1) {
#pragma unroll
    for (int j = 0; j < 8; j++) a[j] += __shfl_xor(a[j], m, 64);
  }
  if (eo == 0) {
    float sv = scale[v];
    float o[8];
    if constexpr (GCN) {
      uint4 hv = *(const uint4*)&Hs[(long long)v * F + col * 8];
      float2 p0 = bfunpack(hv.x), p1 = bfunpack(hv.y);
      float2 p2 = bfunpack(hv.z), p3 = bfunpack(hv.w);
      float h[8] = {p0.x,p0.y,p1.x,p1.y,p2.x,p2.y,p3.x,p3.y};
#pragma unroll
      for (int j = 0; j < 8; j++) o[j] = bias[col * 8 + j] + sv * (a[j] + h[j]);
    } else if constexpr (ADD) {
      const float4 t0 = *(const float4*)&addf[(long long)v * F + col * 8];
      const float4 t1 = *(const float4*)&addf[(long long)v * F + col * 8 + 4];
      o[0]=fmaf(sv,a[0],t0.x); o[1]=fmaf(sv,a[1],t0.y);
      o[2]=fmaf(sv,a[2],t0.z); o[3]=fmaf(sv,a[3],t0.w);
      o[4]=fmaf(sv,a[4],t1.x); o[5]=fmaf(sv,a[5],t1.y);
      o[6]=fmaf(sv,a[6],t1.z); o[7]=fmaf(sv,a[7],t1.w);
    } else {
#pragma unroll
      for (int j = 0; j < 8; j++) o[j] = sv * a[j];
    }
    if constexpr (OUTBF) {
      uint4 u;
      u.x = bfpack(o[0], o[1]); u.y = bfpack(o[2], o[3]);
      u.z = bfpack(o[4], o[5]); u.w = bfpack(o[6], o[7]);
      *(uint4*)&outb[(long long)v * F + col * 8] = u;
    } else {
      float4 o0 = {o[0],o[1],o[2],o[3]}, o1 = {o[4],o[5],o[6],o[7]};
      *(float4*)&outf[(long long)v * F + col * 8]     = o0;
      *(float4*)&outf[(long long)v * F + col * 8 + 4] = o1;
    }
  }
}

// ==== gather with fp8 e4m3 neighbor rows (8 fp8 = 8 B/lane) ==================
// GCN: self term from bf16 Hbf + bias, out bf16.  ADD: + addf (f32), out bf16.
template<int F, bool GCN, bool ADD>
__global__ __launch_bounds__(256) void k_gather_fp8(
    const unsigned char* __restrict__ Hf8, const unsigned short* __restrict__ Hbf,
    const float* __restrict__ scale,
    const int* __restrict__ rowptr, const int* __restrict__ eidx,
    const float* __restrict__ bias, const float* __restrict__ addf,
    unsigned short* __restrict__ outb, int n) {
  constexpr int COLS = F / 8;
  constexpr int EPI  = 64 / COLS;
  const int v = blockIdx.x * 4 + (threadIdx.x >> 6);
  if (v >= n) return;
  const int lane = threadIdx.x & 63;
  const int col  = lane % COLS;
  const int eo   = lane / COLS;

  const int lo = rowptr[v], hi = rowptr[v + 1];
  float a[8] = {0.f,0.f,0.f,0.f,0.f,0.f,0.f,0.f};
  int myE = (lo + lane < hi) ? eidx[lo + lane] : 0;
  for (int base = lo; base < hi; base += 64) {
    int cnt = min(hi - base, 64);
    int nxt = (base + 64 + lane < hi) ? eidx[base + 64 + lane] : 0;
#pragma unroll 4
    for (int t = eo; t < cnt; t += EPI) {
      int s = __shfl(myE, t, 64);
      uint2 q = *(const uint2*)&Hf8[(long long)s * F + col * 8];
      f32x2 p0 = __builtin_amdgcn_cvt_pk_f32_fp8(q.x, false);
      f32x2 p1 = __builtin_amdgcn_cvt_pk_f32_fp8(q.x, true);
      f32x2 p2 = __builtin_amdgcn_cvt_pk_f32_fp8(q.y, false);
      f32x2 p3 = __builtin_amdgcn_cvt_pk_f32_fp8(q.y, true);
      a[0]+=p0[0]; a[1]+=p0[1]; a[2]+=p1[0]; a[3]+=p1[1];
      a[4]+=p2[0]; a[5]+=p2[1]; a[6]+=p3[0]; a[7]+=p3[1];
    }
    myE = nxt;
  }
#pragma unroll
  for (int m = COLS; m < 64; m <<= 1) {
#pragma unroll
    for (int j = 0; j < 8; j++) a[j] += __shfl_xor(a[j], m, 64);
  }
  if (eo == 0) {
    float sv = scale[v];
    float o[8];
    if constexpr (GCN) {
      uint4 hv = *(const uint4*)&Hbf[(long long)v * F + col * 8];
      float2 p0 = bfunpack(hv.x), p1 = bfunpack(hv.y);
      float2 p2 = bfunpack(hv.z), p3 = bfunpack(hv.w);
      float h[8] = {p0.x,p0.y,p1.x,p1.y,p2.x,p2.y,p3.x,p3.y};
#pragma unroll
      for (int j = 0; j < 8; j++) o[j] = bias[col * 8 + j] + sv * (a[j] + h[j]);
    } else if constexpr (ADD) {
      const float4 t0 = *(const float4*)&addf[(long long)v * F + col * 8];
      const float4 t1 = *(const float4*)&addf[(long long)v * F + col * 8 + 4];
      o[0]=fmaf(sv,a[0],t0.x); o[1]=fmaf(sv,a[1],t0.y);
      o[2]=fmaf(sv,a[2],t0.z); o[3]=fmaf(sv,a[3],t0.w);
      o[4]=fmaf(sv,a[4],t1.x); o[5]=fmaf(sv,a[5],t1.y);
      o[6]=fmaf(sv,a[6],t1.z); o[7]=fmaf(sv,a[7],t1.w);
    } else {
#pragma unroll
      for (int j = 0; j < 8; j++) o[j] = sv * a[j];
    }
    uint4 u;
    u.x = bfpack(o[0], o[1]); u.y = bfpack(o[2], o[3]);
    u.z = bfpack(o[4], o[5]); u.w = bfpack(o[6], o[7]);
    *(uint4*)&outb[(long long)v * F + col * 8] = u;
  }
}

// =======================================================================
// MFMA GEMM: Yb = bf16(prescale * (act(X) @ W)); optional fp8 copy (F8OUT).
// =======================================================================
template<int K, int F, bool XBF, bool BNIN, bool F8OUT>
__global__ __launch_bounds__(256) void k_gemm_mfma(
    const void* __restrict__ Xv, const float* __restrict__ W,
    const float* __restrict__ bnstats, const float* __restrict__ prescale,
    unsigned short* __restrict__ Yb, unsigned char* __restrict__ Yf8, int n) {
  constexpr int SP  = K + 8;      // padded LDS row stride (shorts)
  constexpr int NCT = F / 16;     // col-tiles per wave
  __shared__ unsigned short sX[64 * SP];
  __shared__ unsigned short sWT[F * SP];
  __shared__ float sbn[BNIN ? 2 * K : 1];

  const int row0 = blockIdx.x * 64;
  if constexpr (BNIN) {
    for (int i = threadIdx.x; i < 2 * K; i += 256) sbn[i] = bnstats[i];
    __syncthreads();
  }
  for (int i = threadIdx.x; i < (K / 2) * F; i += 256) {
    int nn = i % F;
    int kk = (i / F) * 2;
    float w0 = W[(long long)kk * F + nn];
    float w1 = W[(long long)(kk + 1) * F + nn];
    *(unsigned*)&sWT[nn * SP + kk] = bfpack(w0, w1);
  }
  for (int i = threadIdx.x; i < 64 * (K / 8); i += 256) {
    int r = i / (K / 8), k8 = (i % (K / 8)) * 8;
    int gr = row0 + r;
    uint4 u = {0, 0, 0, 0};
    if (gr < n) {
      if constexpr (XBF) {
        const unsigned short* X = (const unsigned short*)Xv;
        uint4 raw = *(const uint4*)&X[(long long)gr * K + k8];
        if constexpr (BNIN) {
          float2 p0 = bfunpack(raw.x), p1 = bfunpack(raw.y);
          float2 p2 = bfunpack(raw.z), p3 = bfunpack(raw.w);
          float y[8] = {p0.x,p0.y,p1.x,p1.y,p2.x,p2.y,p3.x,p3.y};
#pragma unroll
          for (int j = 0; j < 8; j++) {
            float t = fmaf(y[j], sbn[k8 + j], sbn[K + k8 + j]);
            y[j] = (t >= 0.f) ? t : LEAK * t;
          }
          u.x = bfpack(y[0], y[1]); u.y = bfpack(y[2], y[3]);
          u.z = bfpack(y[4], y[5]); u.w = bfpack(y[6], y[7]);
        } else {
          u = raw;
        }
      } else {
        const float* X = (const float*)Xv;
        float4 xa = *(const float4*)&X[(long long)gr * K + k8];
        float4 xb = *(const float4*)&X[(long long)gr * K + k8 + 4];
        u.x = bfpack(xa.x, xa.y); u.y = bfpack(xa.z, xa.w);
        u.z = bfpack(xb.x, xb.y); u.w = bfpack(xb.z, xb.w);
      }
    }
    *(uint4*)&sX[r * SP + k8] = u;
  }
  __syncthreads();

  const int wv   = threadIdx.x >> 6;
  const int lane = threadIdx.x & 63;
  const int l16  = lane & 15;
  const int quad = lane >> 4;
  f32x4 acc[NCT];
#pragma unroll
  for (int c = 0; c < NCT; c++) acc[c] = (f32x4){0.f, 0.f, 0.f, 0.f};

#pragma unroll
  for (int k0 = 0; k0 < K; k0 += 32) {
    bf16x8 af = *(const bf16x8*)&sX[(wv * 16 + l16) * SP + k0 + quad * 8];
#pragma unroll
    for (int c = 0; c < NCT; c++) {
      bf16x8 bfr = *(const bf16x8*)&sWT[(c * 16 + l16) * SP + k0 + quad * 8];
      acc[c] = __builtin_amdgcn_mfma_f32_16x16x32_bf16(af, bfr, acc[c], 0, 0, 0);
    }
  }

  const int rbase = row0 + wv * 16 + quad * 4;
  float ps[4];
#pragma unroll
  for (int rg = 0; rg < 4; rg++) {
    int gr = rbase + rg;
    ps[rg] = (prescale && gr < n) ? prescale[gr] : 1.0f;
  }
#pragma unroll
  for (int c = 0; c < NCT; c++) {
    int col = c * 16 + l16;
#pragma unroll
    for (int rg = 0; rg < 4; rg++) {
      int gr = rbase + rg;
      if (gr < n) {
        float val = acc[c][rg] * ps[rg];
        Yb[(long long)gr * F + col] = bfround(val);
        if constexpr (F8OUT) Yf8[(long long)gr * F + col] = f32_to_fp8(val);
      }
    }
  }
}

// ==== SAGE dual MFMA GEMM (BN+lrelu fused): t1=X'@Wl fp8, t2=X'@Wr+bl f32 ===
__global__ __launch_bounds__(256) void k_gemm_sage_mfma(
    const unsigned short* __restrict__ X, const float* __restrict__ Wl,
    const float* __restrict__ Wr, const float* __restrict__ bl,
    const float* __restrict__ bnstats,
    unsigned char* __restrict__ t1f8, float* __restrict__ t2, int n) {
  constexpr int K = 128, F = 64, SP = K + 8, NCT = F / 16;  // 4
  __shared__ unsigned short sX[64 * SP];
  __shared__ unsigned short sWlT[F * SP];
  __shared__ unsigned short sWrT[F * SP];
  __shared__ float sbn[2 * K];

  for (int i = threadIdx.x; i < 2 * K; i += 256) sbn[i] = bnstats[i];
  __syncthreads();
  const int row0 = blockIdx.x * 64;
  for (int i = threadIdx.x; i < (K / 2) * F; i += 256) {
    int nn = i % F;
    int kk = (i / F) * 2;
    *(unsigned*)&sWlT[nn * SP + kk] =
        bfpack(Wl[(long long)kk * F + nn], Wl[(long long)(kk + 1) * F + nn]);
    *(unsigned*)&sWrT[nn * SP + kk] =
        bfpack(Wr[(long long)kk * F + nn], Wr[(long long)(kk + 1) * F + nn]);
  }
  for (int i = threadIdx.x; i < 64 * (K / 8); i += 256) {
    int r = i / (K / 8), k8 = (i % (K / 8)) * 8;
    int gr = row0 + r;
    uint4 u = {0, 0, 0, 0};
    if (gr < n) {
      uint4 raw = *(const uint4*)&X[(long long)gr * K + k8];
      float2 p0 = bfunpack(raw.x), p1 = bfunpack(raw.y);
      float2 p2 = bfunpack(raw.z), p3 = bfunpack(raw.w);
      float y[8] = {p0.x,p0.y,p1.x,p1.y,p2.x,p2.y,p3.x,p3.y};
#pragma unroll
      for (int j = 0; j < 8; j++) {
        float t = fmaf(y[j], sbn[k8 + j], sbn[K + k8 + j]);
        y[j] = (t >= 0.f) ? t : LEAK * t;
      }
      u.x = bfpack(y[0], y[1]); u.y = bfpack(y[2], y[3]);
      u.z = bfpack(y[4], y[5]); u.w = bfpack(y[6], y[7]);
    }
    *(uint4*)&sX[r * SP + k8] = u;
  }
  __syncthreads();

  const int wv   = threadIdx.x >> 6;
  const int lane = threadIdx.x & 63;
  const int l16  = lane & 15;
  const int quad = lane >> 4;
  f32x4 a1[NCT], a2[NCT];
#pragma unroll
  for (int c = 0; c < NCT; c++) {
    a1[c] = (f32x4){0.f, 0.f, 0.f, 0.f};
    a2[c] = (f32x4){0.f, 0.f, 0.f, 0.f};
  }
#pragma unroll
  for (int k0 = 0; k0 < K; k0 += 32) {
    bf16x8 af = *(const bf16x8*)&sX[(wv * 16 + l16) * SP + k0 + quad * 8];
#pragma unroll
    for (int c = 0; c < NCT; c++) {
      bf16x8 bl8 = *(const bf16x8*)&sWlT[(c * 16 + l16) * SP + k0 + quad * 8];
      bf16x8 br8 = *(const bf16x8*)&sWrT[(c * 16 + l16) * SP + k0 + quad * 8];
      a1[c] = __builtin_amdgcn_mfma_f32_16x16x32_bf16(af, bl8, a1[c], 0, 0, 0);
      a2[c] = __builtin_amdgcn_mfma_f32_16x16x32_bf16(af, br8, a2[c], 0, 0, 0);
    }
  }
  const int rbase = row0 + wv * 16 + quad * 4;
#pragma unroll
  for (int c = 0; c < NCT; c++) {
    int col = c * 16 + l16;
    float blv = bl[col];
#pragma unroll
    for (int rg = 0; rg < 4; rg++) {
      int gr = rbase + rg;
      if (gr < n) {
        t1f8[(long long)gr * F + col] = f32_to_fp8(a1[c][rg]);
        t2[(long long)gr * F + col]   = a2[c][rg] + blv;
      }
    }
  }
}

// ---------------- BatchNorm stats (from bf16 pre-BN buffer) ----------------
template<int F>
__global__ __launch_bounds__(256) void k_bn_stats(const unsigned short* __restrict__ Y,
                                                  float* __restrict__ partials, int n) {
  constexpr int FP  = F / 2;
  constexpr int RPB = 256 / FP;
  const int f2 = threadIdx.x % FP;
  const int r0 = threadIdx.x / FP;
  const unsigned* Yu = (const unsigned*)Y;
  float s1a = 0.f, s2a = 0.f, s1b = 0.f, s2b = 0.f;
  for (long long r = (long long)blockIdx.x * RPB + r0; r < n; r += 256LL * RPB) {
    float2 p = bfunpack(Yu[r * FP + f2]);
    s1a += p.x; s2a += p.x * p.x;
    s1b += p.y; s2b += p.y * p.y;
  }
  __shared__ float l1a[256], l2a[256], l1b[256], l2b[256];
  l1a[threadIdx.x] = s1a; l2a[threadIdx.x] = s2a;
  l1b[threadIdx.x] = s1b; l2b[threadIdx.x] = s2b;
  __syncthreads();
  if (r0 == 0) {
#pragma unroll
    for (int i = 1; i < RPB; i++) {
      s1a += l1a[i * FP + f2]; s2a += l2a[i * FP + f2];
      s1b += l1b[i * FP + f2]; s2b += l2b[i * FP + f2];
    }
    float* p = &partials[blockIdx.x * 2 * F];
    p[2 * f2]         = s1a;
    p[2 * f2 + 1]     = s1b;
    p[F + 2 * f2]     = s2a;
    p[F + 2 * f2 + 1] = s2b;
  }
}

__global__ void k_bn_finalize(const float* __restrict__ partials, float* __restrict__ stats,
                              const float* __restrict__ g, const float* __restrict__ be,
                              int F, float invN) {
  int f = threadIdx.x;
  if (f >= F) return;
  float s1 = 0.f, s2 = 0.f;
  for (int b = 0; b < 256; b++) {
    s1 += partials[b * 2 * F + f];
    s2 += partials[b * 2 * F + F + f];
  }
  float m   = s1 * invN;
  float var = s2 * invN - m * m;
  float sc  = g[f] * rsqrtf(var + BNEPS);
  stats[f]     = sc;
  stats[F + f] = be[f] - m * sc;
}

// ---------------- pool (batch sorted; binary search per graph) + link ------
__global__ __launch_bounds__(256) void k_pool2(const float* __restrict__ a4,
                                               const int* __restrict__ batch,
                                               float* __restrict__ gpool, int n) {
  int g = blockIdx.x * 4 + (threadIdx.x >> 6);
  if (g >= NGMAX) return;
  int lane = threadIdx.x & 63;
  int s = 0, e = n;
  while (s < e) { int m = (s + e) >> 1; if (batch[m] < g) s = m + 1; else e = m; }
  int s2 = s, e2 = n;
  while (s2 < e2) { int m = (s2 + e2) >> 1; if (batch[m] < g + 1) s2 = m + 1; else e2 = m; }
  int f = lane & 31, ro = lane >> 5;
  float acc = 0.f;
  for (int r = s + ro; r < s2; r += 2) acc += a4[(long long)r * 32 + f];
  acc += __shfl_xor(acc, 32, 64);
  if (lane < 32) gpool[(long long)g * 32 + f] = acc;
}

__global__ void k_link(const float* __restrict__ g, const int* __restrict__ li0,
                       const int* __restrict__ li1, float* __restrict__ out, int L) {
  int i = blockIdx.x * blockDim.x + threadIdx.x;
  if (i >= L) return;
  const float* a = g + (long long)li0[i] * 32;
  const float* b = g + (long long)li1[i] * 32;
  float s = 0.f;
#pragma unroll
  for (int f = 0; f < 32; f++) s = fmaf(a[f], b[f], s);
  out[i] = 1.0f / (1.0f + expf(-s));
}

// ---------------- launch ----------------
extern "C" void kernel_launch(void* const* d_in, const int* in_sizes, int n_in,
                              void* d_out, int out_size, void* d_ws, size_t ws_size,
                              hipStream_t stream) {
  const float* x   = (const float*)d_in[0];
  const int* ei    = (const int*)d_in[1];
  const int* batch = (const int*)d_in[2];
  const int* li    = (const int*)d_in[3];
  const float* W1  = (const float*)d_in[5];
  const float* b1  = (const float*)d_in[6];
  const float* g1  = (const float*)d_in[7];
  const float* be1 = (const float*)d_in[8];
  const float* Wl2 = (const float*)d_in[9];
  const float* bl2 = (const float*)d_in[10];
  const float* Wr2 = (const float*)d_in[11];
  const float* g2  = (const float*)d_in[12];
  const float* be2 = (const float*)d_in[13];
  const float* W3  = (const float*)d_in[14];
  const float* b3  = (const float*)d_in[15];
  const float* g3  = (const float*)d_in[16];
  const float* be3 = (const float*)d_in[17];
  const float* W4  = (const float*)d_in[18];
  const float* b4  = (const float*)d_in[19];

  const int n = in_sizes[0] / 128;   // 50000
  const int E = in_sizes[1] / 2;     // 800000
  const int L = in_sizes[3] / 2;     // 1000
  const int* src = ei;
  const int* dst = ei + E;
  const int* li0 = li;
  const int* li1 = li + L;
  const int NBK = (n + 255) / 256;   // dst buckets (<=256 for n<=65536)

  char* base = (char*)d_ws;
  size_t off = 0;
  auto alloc = [&](size_t bytes) -> void* {
    void* p = (void*)(base + off);
    off = (off + bytes + 255) & ~(size_t)255;
    return p;
  };
  int*   H      = (int*)alloc((size_t)NBK * NCH * 4);
  int*   O      = (int*)alloc((size_t)NBK * NCH * 4);
  int*   hsum   = (int*)alloc((size_t)1024 * 4);
  int*   ebuf   = (int*)alloc((size_t)E * 4);
  int*   eidx   = (int*)alloc((size_t)E * 4);
  int*   rowptr = (int*)alloc((size_t)(n + 1) * 4);
  float* dinv   = (float*)alloc((size_t)n * 4);
  float* invcnt = (float*)alloc((size_t)n * 4);
  float* stats1 = (float*)alloc(256 * 4);
  float* stats2 = (float*)alloc(128 * 4);
  float* stats3 = (float*)alloc(64 * 4);
  float* partials = (float*)alloc((size_t)256 * 256 * 4);
  float* gpool  = (float*)alloc((size_t)NGMAX * 32 * 4);
  unsigned short* h1b  = (unsigned short*)alloc((size_t)n * 128 * 2); // dinv*(x@W1) bf16
  unsigned char*  h1f8 = (unsigned char*)alloc((size_t)n * 128);     // same, fp8 e4m3
  unsigned short* a1b  = (unsigned short*)alloc((size_t)n * 128 * 2); // pre-BN a1
  unsigned char*  t1f8 = (unsigned char*)alloc((size_t)n * 64);      // h1'@Wl2 fp8
  float*          t2f  = (float*)alloc((size_t)n * 64 * 4);          // h1'@Wr2+bl2
  unsigned short* h2b  = (unsigned short*)alloc((size_t)n * 64 * 2); // pre-BN h2
  unsigned short* h3gb = (unsigned short*)alloc((size_t)n * 32 * 2); // dinv*(h2'@W3)
  unsigned short* a3b  = (unsigned short*)alloc((size_t)n * 32 * 2); // pre-BN a3
  unsigned short* h4b  = (unsigned short*)alloc((size_t)n * 32 * 2); // dinv*(h3'@W4)
  float*          a4f  = (float*)alloc((size_t)n * 32 * 4);          // a4 (fp32)
  (void)ws_size; (void)n_in; (void)out_size;

  const int BT = 256;
  auto cdiv = [](long long a, long long b) { return (int)((a + b - 1) / b); };
  const int GB  = cdiv(n, 4);                 // gather grid
  const int GM  = cdiv(n, 64);                // mfma gemm grid
  const int MH  = NBK * NCH;                  // histogram elements
  const int NBH = cdiv(MH, 256);              // scan blocks

  // ---- CSR build: bucketed counting sort ----
  k_hist<<<NCH, 256, 0, stream>>>(dst, H, E, NBK);
  k_gscan1<<<NBH, 256, 0, stream>>>(H, hsum, MH);
  k_gscan2<<<1, 256, 0, stream>>>(hsum, NBH);
  k_gscan3<<<NBH, 256, 0, stream>>>(H, hsum, O, MH);
  k_scatter_bkt<<<NCH, 256, 0, stream>>>(src, dst, O, ebuf, E, NBK);
  k_fill2<<<NBK, 256, 0, stream>>>(ebuf, O, eidx, rowptr, dinv, invcnt, E, n, NBK);

  // ---- L1: GCN 128->128 (MFMA; emits bf16 + fp8 copies) ----
  k_gemm_mfma<128,128,false,false,true><<<GM, 256, 0, stream>>>(
      x, W1, nullptr, dinv, h1b, h1f8, n);
  k_gather_fp8<128,true,false><<<GB, 256, 0, stream>>>(
      h1f8, h1b, dinv, rowptr, eidx, b1, nullptr, a1b, n);
  k_bn_stats<128><<<256, 256, 0, stream>>>(a1b, partials, n);
  k_bn_finalize<<<1, 128, 0, stream>>>(partials, stats1, g1, be1, 128, 1.0f / n);

  // ---- L2: SAGE 128->64 (MFMA dual, BN1+lrelu fused; t1 fp8) ----
  k_gemm_sage_mfma<<<GM, 256, 0, stream>>>(a1b, Wl2, Wr2, bl2, stats1, t1f8, t2f, n);
  k_gather_fp8<64,false,true><<<GB, 256, 0, stream>>>(
      t1f8, nullptr, invcnt, rowptr, eidx, nullptr, t2f, h2b, n);
  k_bn_stats<64><<<256, 256, 0, stream>>>(h2b, partials, n);
  k_bn_finalize<<<1, 64, 0, stream>>>(partials, stats2, g2, be2, 64, 1.0f / n);

  // ---- L3: GCN 64->32 (MFMA, BN2+lrelu fused) ----
  k_gemm_mfma<64,32,true,true,false><<<GM, 256, 0, stream>>>(
      h2b, W3, stats2, dinv, h3gb, nullptr, n);
  k_gather<32,true,true,false><<<GB, 256, 0, stream>>>(
      h3gb, dinv, rowptr, eidx, b3, nullptr, nullptr, a3b, n);
  k_bn_stats<32><<<256, 256, 0, stream>>>(a3b, partials, n);
  k_bn_finalize<<<1, 32, 0, stream>>>(partials, stats3, g3, be3, 32, 1.0f / n);

  // ---- L4: GCN 32->32 (MFMA, BN3+lrelu fused), fp32 out via gather ----
  k_gemm_mfma<32,32,true,true,false><<<GM, 256, 0, stream>>>(
      a3b, W4, stats3, dinv, h4b, nullptr, n);
  k_gather<32,true,false,false><<<GB, 256, 0, stream>>>(
      h4b, dinv, rowptr, eidx, b4, nullptr, a4f, nullptr, n);

  // ---- pool (no atomics; batch sorted) + link ----
  k_pool2<<<NGMAX / 4, 256, 0, stream>>>(a4f, batch, gpool, n);
  k_link<<<cdiv(L, BT), BT, 0, stream>>>(gpool, li0, li1, (float*)d_out, L);
}